// Round 5
// baseline (117.600 us; speedup 1.0000x reference)
//
#include <hip/hip_runtime.h>
#include <hip/hip_bf16.h>

// Problem shapes
#define B_SZ 64
#define T_PTS 300
#define N_SEG 299
#define VM 34            // 17*2
#define NPATH (B_SZ*VM)  // 2176
#define SIGC 120         // 3+9+27+81
#define FAN1 4080        // 34*120
#define H1 512
#define NOUT 155
#define CHUNK 5          // segments per lane (64*5=320 >= 299)
#define TT 75            // transpose t-tile (300/4)
#define KSPL 48          // gemm1 K-splits
#define KW 85            // k per wave (48*85 = 4080)
#define JPW 8            // gemm1 j-rows per wave

// ---------------------------------------------------------------------------
// Absorb one linear segment with increment d into state a1..a4.
// Horner-factored: a segment signature is exp(d), so every level is a tensor
// power of d and the update nests in the trailing index:
//   n4[ijkl] = a4 + d[l]*X[ijk], X = a3 + d[k]*Y[ij], Y = a2/2 + d[j]*Z[i],
//   Z = a1/6 + d[i]/24          (expansion == a3(x)d + a2(x)d^2/2! + ...)
// 189 VALU ops vs ~480 for the explicit-tensor-power form.
// ---------------------------------------------------------------------------
__device__ __forceinline__ void sig_append(float a1[3], float a2[9], float a3[27], float a4[81],
                                           float d0, float d1, float d2) {
  const float d[3] = {d0, d1, d2};

  // Level 4 (uses OLD a1,a2,a3)
  float Z[3], Y[9], X[27];
#pragma unroll
  for (int i = 0; i < 3; i++) Z[i] = fmaf(d[i], 1.0f / 24.0f, (1.0f / 6.0f) * a1[i]);
#pragma unroll
  for (int e = 0; e < 9; e++) Y[e] = fmaf(d[e % 3], Z[e / 3], 0.5f * a2[e]);
#pragma unroll
  for (int e = 0; e < 27; e++) X[e] = fmaf(d[e % 3], Y[e / 3], a3[e]);
#pragma unroll
  for (int e = 0; e < 81; e++) a4[e] = fmaf(d[e % 3], X[e / 3], a4[e]);

  // Level 3 (uses OLD a1,a2)
  float Z3[3], Y3[9];
#pragma unroll
  for (int i = 0; i < 3; i++) Z3[i] = fmaf(d[i], 1.0f / 6.0f, 0.5f * a1[i]);
#pragma unroll
  for (int e = 0; e < 9; e++) Y3[e] = fmaf(d[e % 3], Z3[e / 3], a2[e]);
#pragma unroll
  for (int e = 0; e < 27; e++) a3[e] = fmaf(d[e % 3], Y3[e / 3], a3[e]);

  // Level 2 (uses OLD a1)
  float Z2[3];
#pragma unroll
  for (int i = 0; i < 3; i++) Z2[i] = fmaf(d[i], 0.5f, a1[i]);
#pragma unroll
  for (int e = 0; e < 9; e++) a2[e] = fmaf(d[e % 3], Z2[e / 3], a2[e]);

#pragma unroll
  for (int i = 0; i < 3; i++) a1[i] += d[i];
}

// ---------------------------------------------------------------------------
// Cross-lane fetch for the Chen combine.
//   OFF < 16 : DPP row_shl:OFF -> lane i reads lane i+OFF within its 16-lane
//              row; out-of-row lanes get 0 (= Chen identity). VALU pipe.
//   OFF >= 16: __shfl_xor butterfly (VERIFIED correct in R2/R3). Only lane
//              0's chain is consumed; its partners (lane 16 pre-round,
//              lane 32 post-round-16) are always valid suffix products, so
//              no mask is needed.
// NOTE (R4 post-mortem): v_permlane16_swap-based butterflies FAILED here —
// the swap direction (odd-rows-of-vdst <-> even-rows-of-src) leaves lane 0
// holding its own state. Do not reintroduce without an isolated semantics
// probe.
// ---------------------------------------------------------------------------
template <int OFF>
__device__ __forceinline__ float lane_down(float x) {
  if constexpr (OFF < 16) {
    return __int_as_float(__builtin_amdgcn_update_dpp(
        0, __float_as_int(x), 0x100 + OFF /*row_shl:OFF*/, 0xF, 0xF, true));
  } else {
    return __shfl_xor(x, OFF);
  }
}

// One Chen-combine round: state <- state (x) fetched-state.
template <int OFF>
__device__ __forceinline__ void chen_round(float a1[3], float a2[9], float a3[27], float a4[81]) {
  float B1[3], B2[9], B3[27];
#pragma unroll
  for (int i = 0; i < 3; i++) B1[i] = lane_down<OFF>(a1[i]);
#pragma unroll
  for (int i = 0; i < 9; i++) B2[i] = lane_down<OFF>(a2[i]);
#pragma unroll
  for (int i = 0; i < 27; i++) B3[i] = lane_down<OFF>(a3[i]);

#pragma unroll
  for (int e = 0; e < 81; e++) {
    const float b4 = lane_down<OFF>(a4[e]);  // reads pre-update a4[e]
    float v = a4[e] + b4;
    v = fmaf(a3[e / 3], B1[e % 3], v);
    v = fmaf(a2[e / 9], B2[e % 9], v);
    v = fmaf(a1[e / 27], B3[e % 27], v);
    a4[e] = v;
  }
#pragma unroll
  for (int e = 0; e < 27; e++) {
    float v = a3[e] + B3[e];
    v = fmaf(a2[e / 3], B1[e % 3], v);
    v = fmaf(a1[e / 9], B2[e % 9], v);
    a3[e] = v;
  }
#pragma unroll
  for (int e = 0; e < 9; e++) a2[e] = fmaf(a1[e / 3], B1[e % 3], a2[e] + B2[e]);
#pragma unroll
  for (int i = 0; i < 3; i++) a1[i] += B1[i];
}

// ---------------------------------------------------------------------------
// Kernel 0: transpose (B,C,T,V,M) -> (P=B*VM, T, C) contiguous paths; fused
// ht = broadcast(b1) init (gemm1 accumulates atomically on top).
// ---------------------------------------------------------------------------
__global__ __launch_bounds__(256) void transpose_kernel(const float* __restrict__ inp,
                                                        float* __restrict__ tp,
                                                        const float* __restrict__ b1,
                                                        float* __restrict__ ht) {
  const int b = blockIdx.x;       // 0..63
  const int tile = blockIdx.y;    // 0..3
  const int t0 = tile * TT;
  const int tid = threadIdx.x;
  __shared__ float lds[3 * TT * VM];  // 7650 floats = 30.6 KB

  const float* src = inp + (size_t)b * 3 * T_PTS * VM;
  for (int idx = tid; idx < 3 * TT * VM; idx += 256) {
    const int c = idx / (TT * VM);
    const int rem = idx - c * (TT * VM);
    lds[idx] = src[(c * T_PTS + t0) * VM + rem];
  }
  __syncthreads();

  for (int idx = tid; idx < VM * TT * 3; idx += 256) {
    const int vm = idx / (TT * 3);
    const int i = idx - vm * (TT * 3);
    const int tt = i / 3;
    const int c = i - tt * 3;
    tp[((size_t)(b * VM + vm) * T_PTS + t0 + tt) * 3 + c] = lds[(c * TT + tt) * VM + vm];
  }

  if (tile == 0) {
    // ht[j][bb] = b1[j] for j in [8b, 8b+8)
    for (int idx = tid; idx < 8 * 64; idx += 256)
      ht[(size_t)(8 * b) * 64 + idx] = b1[8 * b + (idx >> 6)];
  }
}

// ---------------------------------------------------------------------------
// Kernel 1: signatures. One PATH per WAVE, one wave per block (2176 blocks).
// 64 lanes x 5 Horner-appends each, then the Chen combine: 4 DPP row-local
// Kogge-Stone rounds (off 1,2,4,8) + 2 maskless __shfl_xor butterfly rounds
// (off 16,32). Output TRANSPOSED: St[k][b], k = vm*120 + c.
// ---------------------------------------------------------------------------
__global__ __launch_bounds__(64)
__attribute__((amdgpu_waves_per_eu(1)))
void sig_kernel(const float* __restrict__ tp, float* __restrict__ St) {
  const int lane = threadIdx.x & 63;
  const int p = blockIdx.x;         // 2176 paths
  const int t0 = lane * CHUNK;

  const float* bp = tp + (size_t)p * (T_PTS * 3) + t0 * 3;

  float a1[3], a2[9], a3[27], a4[81];
#pragma unroll
  for (int i = 0; i < 3; i++) a1[i] = 0.f;
#pragma unroll
  for (int i = 0; i < 9; i++) a2[i] = 0.f;
#pragma unroll
  for (int i = 0; i < 27; i++) a3[i] = 0.f;
#pragma unroll
  for (int i = 0; i < 81; i++) a4[i] = 0.f;

  float x0 = bp[0], x1 = bp[1], x2 = bp[2];
#pragma unroll
  for (int s = 0; s < CHUNK; s++) {
    // Over-reads (up to point 320) stay inside ws (St follows tp) and are
    // masked off below.
    const float y0 = bp[3 * s + 3];
    const float y1 = bp[3 * s + 4];
    const float y2 = bp[3 * s + 5];
    const bool valid = (t0 + s) < N_SEG;
    const float d0 = valid ? (y0 - x0) : 0.0f;
    const float d1 = valid ? (y1 - x1) : 0.0f;
    const float d2 = valid ? (y2 - x2) : 0.0f;
    sig_append(a1, a2, a3, a4, d0, d1, d2);
    x0 = y0; x1 = y1; x2 = y2;
  }

  // Row-local suffix Chen product (16-lane Kogge-Stone via DPP).
  chen_round<1>(a1, a2, a3, a4);
  chen_round<2>(a1, a2, a3, a4);
  chen_round<4>(a1, a2, a3, a4);
  chen_round<8>(a1, a2, a3, a4);
  // Cross-row butterfly: lane 0 <- S(0..31) <- S(0..63).
  chen_round<16>(a1, a2, a3, a4);
  chen_round<32>(a1, a2, a3, a4);

  if (lane == 0) {
    const int b = p / VM;
    const int vm = p - b * VM;
    float* dst = St + (size_t)(vm * SIGC) * 64 + b;  // St[(vm*120+i)*64 + b]
#pragma unroll
    for (int i = 0; i < 3; i++) dst[(size_t)i * 64] = a1[i];
#pragma unroll
    for (int i = 0; i < 9; i++) dst[(size_t)(3 + i) * 64] = a2[i];
#pragma unroll
    for (int i = 0; i < 27; i++) dst[(size_t)(12 + i) * 64] = a3[i];
#pragma unroll
    for (int i = 0; i < 81; i++) dst[(size_t)(39 + i) * 64] = a4[i];
  }
}

// ---------------------------------------------------------------------------
// Kernel 2: ht[j][b] += sum_k St[k][b] * W1[j][k].  lane = b (M=64=wave).
// 3072 waves: 48 K-splits (85 k each) x 64 j-groups (8 j each) -> 3
// waves/SIMD. 8 rows per wave halves the St L2 traffic vs 4 rows
// (134 MB -> 67 MB) while sv[85] stays register-resident (static indices);
// W1 rows are wave-uniform streams (scalar loads). 8 independent FMA
// chains interleaved in the inner unroll. Coalesced atomicAdd epilogue
// onto the b1-initialized ht (48 adds/element, order-independent).
// ---------------------------------------------------------------------------
__global__ __launch_bounds__(256) void gemm1_kernel(const float* __restrict__ St,
                                                    const float* __restrict__ W1,
                                                    float* __restrict__ ht) {
  const int lane = threadIdx.x & 63;
  int wave_id = (blockIdx.x * 256 + threadIdx.x) >> 6;        // 0..3071
  wave_id = __builtin_amdgcn_readfirstlane(wave_id);          // force SGPR
  const int ks = wave_id >> 6;    // 0..47  (k-range of 85)
  const int jg = wave_id & 63;    // 0..63  (8 j's each)
  const int k0 = ks * KW;

  const float* stp = St + (size_t)k0 * 64 + lane;
  const float* w[JPW];
#pragma unroll
  for (int r = 0; r < JPW; r++) w[r] = W1 + (size_t)(jg * JPW + r) * FAN1 + k0;  // uniform -> s_load

  float sv[KW];
#pragma unroll
  for (int i = 0; i < KW; i++) sv[i] = stp[(size_t)i * 64];

  float acc[JPW];
#pragma unroll
  for (int r = 0; r < JPW; r++) acc[r] = 0.f;

#pragma unroll
  for (int i = 0; i < KW; i++) {
#pragma unroll
    for (int r = 0; r < JPW; r++) acc[r] = fmaf(sv[i], w[r][i], acc[r]);
  }

  float* hp = ht + (size_t)(jg * JPW) * 64 + lane;
#pragma unroll
  for (int r = 0; r < JPW; r++) atomicAdd(hp + r * 64, acc[r]);
}

// ---------------------------------------------------------------------------
// Kernel 3: out[b][j] = sum_k2 ht[k2][b] * W2[j][k2] + b2[j].  lane = b.
// Block = one j; 4 waves split k2 (128 each); LDS partial reduce; single
// non-atomic store (no out-init needed).
// ---------------------------------------------------------------------------
__global__ __launch_bounds__(256) void gemm2_kernel(const float* __restrict__ ht,
                                                    const float* __restrict__ W2,
                                                    const float* __restrict__ b2,
                                                    float* __restrict__ out) {
  const int j = blockIdx.x;              // 0..154
  const int lane = threadIdx.x & 63;
  int w = threadIdx.x >> 6;              // 0..3
  w = __builtin_amdgcn_readfirstlane(w);
  __shared__ float red[4][64];

  const float* htp = ht + (size_t)(w * 128) * 64 + lane;
  const float* w2r = W2 + (size_t)j * H1 + w * 128;  // uniform -> s_load
  float acc = 0.f;
#pragma unroll 8
  for (int k = 0; k < 128; k++) acc = fmaf(w2r[k], htp[(size_t)k * 64], acc);

  red[w][lane] = acc;
  __syncthreads();
  if (threadIdx.x < 64) {
    const float tot = red[0][lane] + red[1][lane] + red[2][lane] + red[3][lane];
    out[(size_t)lane * NOUT + j] = tot + b2[j];
  }
}

// ---------------------------------------------------------------------------
extern "C" void kernel_launch(void* const* d_in, const int* in_sizes, int n_in,
                              void* d_out, int out_size, void* d_ws, size_t ws_size,
                              hipStream_t stream) {
  const float* inp = (const float*)d_in[0];  // (64,3,300,17,2)
  const float* W1  = (const float*)d_in[1];  // (512,4080)
  const float* b1  = (const float*)d_in[2];  // (512,)
  const float* W2  = (const float*)d_in[3];  // (155,512)
  const float* b2  = (const float*)d_in[4];  // (155,)
  float* out = (float*)d_out;                // (64,155)

  // ws layout (floats): tp | St | ht   (~9.0 MB total)
  float* tpbuf = (float*)d_ws;                       // 2176*900
  float* St    = tpbuf + (size_t)NPATH * T_PTS * 3;  // 4080*64
  float* ht    = St + (size_t)FAN1 * 64;             // 512*64

  transpose_kernel<<<dim3(B_SZ, 4), 256, 0, stream>>>(inp, tpbuf, b1, ht);
  sig_kernel<<<NPATH, 64, 0, stream>>>(tpbuf, St);
  gemm1_kernel<<<KSPL * 64 / 4, 256, 0, stream>>>(St, W1, ht);
  gemm2_kernel<<<NOUT, 256, 0, stream>>>(ht, W2, b2, out);
}

// Round 6
// 114.164 us; speedup vs baseline: 1.0301x; 1.0301x over previous
//
#include <hip/hip_runtime.h>
#include <hip/hip_bf16.h>

// Problem shapes
#define B_SZ 64
#define T_PTS 300
#define N_SEG 299        // last point index / number of segments
#define VM 34            // 17*2
#define NPATH (B_SZ*VM)  // 2176
#define SIGC 120         // 3+9+27+81
#define FAN1 4080        // 34*120
#define H1 512
#define NOUT 155
#define CHUNK 5          // segments per lane (64*5=320 >= 299)
#define KSPL 48          // gemm1 K-splits
#define KW 85            // k per wave (48*85 = 4080)
#define JPW 8            // gemm1 j-rows per wave

// ---------------------------------------------------------------------------
// Absorb one linear segment with increment d into state a1..a4.
// Horner-factored: a segment signature is exp(d), so every level is a tensor
// power of d and the update nests in the trailing index:
//   n4[ijkl] = a4 + d[l]*X[ijk], X = a3 + d[k]*Y[ij], Y = a2/2 + d[j]*Z[i],
//   Z = a1/6 + d[i]/24          (expansion == a3(x)d + a2(x)d^2/2! + ...)
// 189 VALU ops vs ~480 for the explicit-tensor-power form.
// ---------------------------------------------------------------------------
__device__ __forceinline__ void sig_append(float a1[3], float a2[9], float a3[27], float a4[81],
                                           float d0, float d1, float d2) {
  const float d[3] = {d0, d1, d2};

  // Level 4 (uses OLD a1,a2,a3)
  float Z[3], Y[9], X[27];
#pragma unroll
  for (int i = 0; i < 3; i++) Z[i] = fmaf(d[i], 1.0f / 24.0f, (1.0f / 6.0f) * a1[i]);
#pragma unroll
  for (int e = 0; e < 9; e++) Y[e] = fmaf(d[e % 3], Z[e / 3], 0.5f * a2[e]);
#pragma unroll
  for (int e = 0; e < 27; e++) X[e] = fmaf(d[e % 3], Y[e / 3], a3[e]);
#pragma unroll
  for (int e = 0; e < 81; e++) a4[e] = fmaf(d[e % 3], X[e / 3], a4[e]);

  // Level 3 (uses OLD a1,a2)
  float Z3[3], Y3[9];
#pragma unroll
  for (int i = 0; i < 3; i++) Z3[i] = fmaf(d[i], 1.0f / 6.0f, 0.5f * a1[i]);
#pragma unroll
  for (int e = 0; e < 9; e++) Y3[e] = fmaf(d[e % 3], Z3[e / 3], a2[e]);
#pragma unroll
  for (int e = 0; e < 27; e++) a3[e] = fmaf(d[e % 3], Y3[e / 3], a3[e]);

  // Level 2 (uses OLD a1)
  float Z2[3];
#pragma unroll
  for (int i = 0; i < 3; i++) Z2[i] = fmaf(d[i], 0.5f, a1[i]);
#pragma unroll
  for (int e = 0; e < 9; e++) a2[e] = fmaf(d[e % 3], Z2[e / 3], a2[e]);

#pragma unroll
  for (int i = 0; i < 3; i++) a1[i] += d[i];
}

// ---------------------------------------------------------------------------
// Cross-lane fetch for the Chen combine.
//   OFF < 16 : DPP row_shl:OFF -> lane i reads lane i+OFF within its 16-lane
//              row; out-of-row lanes get 0 (= Chen identity). VALU pipe.
//   OFF >= 16: __shfl_xor butterfly (VERIFIED correct in R2/R3/R5). Only
//              lane 0's chain is consumed; its partners (lane 16 pre-round,
//              lane 32 post-round-16) are always valid suffix products.
// NOTE (R4 post-mortem): v_permlane16_swap-based butterflies FAILED here —
// wrong swap direction left lane 0 holding its own state. Do not
// reintroduce without an isolated semantics probe.
// ---------------------------------------------------------------------------
template <int OFF>
__device__ __forceinline__ float lane_down(float x) {
  if constexpr (OFF < 16) {
    return __int_as_float(__builtin_amdgcn_update_dpp(
        0, __float_as_int(x), 0x100 + OFF /*row_shl:OFF*/, 0xF, 0xF, true));
  } else {
    return __shfl_xor(x, OFF);
  }
}

// One Chen-combine round: state <- state (x) fetched-state.
template <int OFF>
__device__ __forceinline__ void chen_round(float a1[3], float a2[9], float a3[27], float a4[81]) {
  float B1[3], B2[9], B3[27];
#pragma unroll
  for (int i = 0; i < 3; i++) B1[i] = lane_down<OFF>(a1[i]);
#pragma unroll
  for (int i = 0; i < 9; i++) B2[i] = lane_down<OFF>(a2[i]);
#pragma unroll
  for (int i = 0; i < 27; i++) B3[i] = lane_down<OFF>(a3[i]);

#pragma unroll
  for (int e = 0; e < 81; e++) {
    const float b4 = lane_down<OFF>(a4[e]);  // reads pre-update a4[e]
    float v = a4[e] + b4;
    v = fmaf(a3[e / 3], B1[e % 3], v);
    v = fmaf(a2[e / 9], B2[e % 9], v);
    v = fmaf(a1[e / 27], B3[e % 27], v);
    a4[e] = v;
  }
#pragma unroll
  for (int e = 0; e < 27; e++) {
    float v = a3[e] + B3[e];
    v = fmaf(a2[e / 3], B1[e % 3], v);
    v = fmaf(a1[e / 9], B2[e % 9], v);
    a3[e] = v;
  }
#pragma unroll
  for (int e = 0; e < 9; e++) a2[e] = fmaf(a1[e / 3], B1[e % 3], a2[e] + B2[e]);
#pragma unroll
  for (int i = 0; i < 3; i++) a1[i] += B1[i];
}

// ---------------------------------------------------------------------------
// Kernel 1: signatures, reading inp DIRECTLY (no transpose stage).
// inp layout: (B, C, T, V*M) -> element ((b*3+c)*300 + t)*34 + vm.
// Per-lane loads are strided (one element per cacheline) but inp is 9.8 MB
// (LLC-resident) and this kernel is VALU-bound at ~2 waves/SIMD — the load
// latency hides under ~4000 cycles of signature arithmetic.
// One PATH per WAVE (2176 blocks). 64 lanes x 5 Horner-appends, then the
// Chen combine: 4 DPP row rounds (off 1,2,4,8) + 2 __shfl_xor butterfly
// rounds (off 16,32). t-indices clamped to 299 (no over-reads); invalid
// segments get d=0 (identity). First 512 blocks also zero their ht row
// (stream-ordered before gemm1's atomics; b1 is folded into gemm2).
// Output TRANSPOSED: St[k][b], k = vm*120 + c.
// ---------------------------------------------------------------------------
__global__ __launch_bounds__(64)
__attribute__((amdgpu_waves_per_eu(1)))
void sig_kernel(const float* __restrict__ inp, float* __restrict__ St,
                float* __restrict__ ht) {
  const int lane = threadIdx.x & 63;
  const int p = blockIdx.x;         // 2176 paths
  if (p < H1) ht[(size_t)p * 64 + lane] = 0.0f;  // zero-init for gemm1 atomics

  const int b = p / VM;
  const int vm = p - b * VM;
  const int t0 = lane * CHUNK;

  // base points at (b, c=0, t=0, vm); channel stride = T_PTS*VM = 10200,
  // t stride = VM = 34 (floats).
  const float* base = inp + (size_t)b * 3 * T_PTS * VM + vm;

  // Clamped point indices for this lane's 6 points.
  int tv[CHUNK + 1];
#pragma unroll
  for (int s = 0; s <= CHUNK; s++) {
    const int t = t0 + s;
    tv[s] = t < N_SEG ? t : N_SEG;
  }

  float a1[3], a2[9], a3[27], a4[81];
#pragma unroll
  for (int i = 0; i < 3; i++) a1[i] = 0.f;
#pragma unroll
  for (int i = 0; i < 9; i++) a2[i] = 0.f;
#pragma unroll
  for (int i = 0; i < 27; i++) a3[i] = 0.f;
#pragma unroll
  for (int i = 0; i < 81; i++) a4[i] = 0.f;

  float x0 = base[0 * T_PTS * VM + tv[0] * VM];
  float x1 = base[1 * T_PTS * VM + tv[0] * VM];
  float x2 = base[2 * T_PTS * VM + tv[0] * VM];
#pragma unroll
  for (int s = 0; s < CHUNK; s++) {
    const float y0 = base[0 * T_PTS * VM + tv[s + 1] * VM];
    const float y1 = base[1 * T_PTS * VM + tv[s + 1] * VM];
    const float y2 = base[2 * T_PTS * VM + tv[s + 1] * VM];
    const bool valid = (t0 + s) < N_SEG;
    const float d0 = valid ? (y0 - x0) : 0.0f;
    const float d1 = valid ? (y1 - x1) : 0.0f;
    const float d2 = valid ? (y2 - x2) : 0.0f;
    sig_append(a1, a2, a3, a4, d0, d1, d2);
    x0 = y0; x1 = y1; x2 = y2;
  }

  // Row-local suffix Chen product (16-lane Kogge-Stone via DPP).
  chen_round<1>(a1, a2, a3, a4);
  chen_round<2>(a1, a2, a3, a4);
  chen_round<4>(a1, a2, a3, a4);
  chen_round<8>(a1, a2, a3, a4);
  // Cross-row butterfly: lane 0 <- S(0..31) <- S(0..63).
  chen_round<16>(a1, a2, a3, a4);
  chen_round<32>(a1, a2, a3, a4);

  if (lane == 0) {
    float* dst = St + (size_t)(vm * SIGC) * 64 + b;  // St[(vm*120+i)*64 + b]
#pragma unroll
    for (int i = 0; i < 3; i++) dst[(size_t)i * 64] = a1[i];
#pragma unroll
    for (int i = 0; i < 9; i++) dst[(size_t)(3 + i) * 64] = a2[i];
#pragma unroll
    for (int i = 0; i < 27; i++) dst[(size_t)(12 + i) * 64] = a3[i];
#pragma unroll
    for (int i = 0; i < 81; i++) dst[(size_t)(39 + i) * 64] = a4[i];
  }
}

// ---------------------------------------------------------------------------
// Kernel 2: ht[j][b] += sum_k St[k][b] * W1[j][k].  lane = b (M=64=wave).
// 3072 waves: 48 K-splits (85 k each) x 64 j-groups (8 j each). sv[85]
// register-resident (static indices); W1 rows are wave-uniform streams
// (scalar loads). 8 independent FMA chains. Coalesced atomicAdd epilogue
// onto the zero-initialized ht (48 adds/element, order-independent).
// ---------------------------------------------------------------------------
__global__ __launch_bounds__(256) void gemm1_kernel(const float* __restrict__ St,
                                                    const float* __restrict__ W1,
                                                    float* __restrict__ ht) {
  const int lane = threadIdx.x & 63;
  int wave_id = (blockIdx.x * 256 + threadIdx.x) >> 6;        // 0..3071
  wave_id = __builtin_amdgcn_readfirstlane(wave_id);          // force SGPR
  const int ks = wave_id >> 6;    // 0..47  (k-range of 85)
  const int jg = wave_id & 63;    // 0..63  (8 j's each)
  const int k0 = ks * KW;

  const float* stp = St + (size_t)k0 * 64 + lane;
  const float* w[JPW];
#pragma unroll
  for (int r = 0; r < JPW; r++) w[r] = W1 + (size_t)(jg * JPW + r) * FAN1 + k0;  // uniform -> s_load

  float sv[KW];
#pragma unroll
  for (int i = 0; i < KW; i++) sv[i] = stp[(size_t)i * 64];

  float acc[JPW];
#pragma unroll
  for (int r = 0; r < JPW; r++) acc[r] = 0.f;

#pragma unroll
  for (int i = 0; i < KW; i++) {
#pragma unroll
    for (int r = 0; r < JPW; r++) acc[r] = fmaf(sv[i], w[r][i], acc[r]);
  }

  float* hp = ht + (size_t)(jg * JPW) * 64 + lane;
#pragma unroll
  for (int r = 0; r < JPW; r++) atomicAdd(hp + r * 64, acc[r]);
}

// ---------------------------------------------------------------------------
// Kernel 3: out[b][j] = sum_k2 (ht[k2][b] + b1[k2]) * W2[j][k2] + b2[j].
// lane = b. Block = one j; 4 waves split k2 (128 each). The b1 fold is a
// second wave-uniform FMA chain in the same loop (accb identical across
// lanes); red[w] = acc + accb so the existing LDS reduce also sums the
// b1·W2[j] correction. Single non-atomic store.
// ---------------------------------------------------------------------------
__global__ __launch_bounds__(256) void gemm2_kernel(const float* __restrict__ ht,
                                                    const float* __restrict__ W2,
                                                    const float* __restrict__ b1,
                                                    const float* __restrict__ b2,
                                                    float* __restrict__ out) {
  const int j = blockIdx.x;              // 0..154
  const int lane = threadIdx.x & 63;
  int w = threadIdx.x >> 6;              // 0..3
  w = __builtin_amdgcn_readfirstlane(w);
  __shared__ float red[4][64];

  const float* htp = ht + (size_t)(w * 128) * 64 + lane;
  const float* w2r = W2 + (size_t)j * H1 + w * 128;  // uniform -> s_load
  const float* b1r = b1 + w * 128;                   // uniform -> s_load
  float acc = 0.f, accb = 0.f;
#pragma unroll 8
  for (int k = 0; k < 128; k++) {
    const float wv = w2r[k];
    acc = fmaf(wv, htp[(size_t)k * 64], acc);
    accb = fmaf(wv, b1r[k], accb);
  }

  red[w][lane] = acc + accb;
  __syncthreads();
  if (threadIdx.x < 64) {
    const float tot = red[0][lane] + red[1][lane] + red[2][lane] + red[3][lane];
    out[(size_t)lane * NOUT + j] = tot + b2[j];
  }
}

// ---------------------------------------------------------------------------
extern "C" void kernel_launch(void* const* d_in, const int* in_sizes, int n_in,
                              void* d_out, int out_size, void* d_ws, size_t ws_size,
                              hipStream_t stream) {
  const float* inp = (const float*)d_in[0];  // (64,3,300,17,2)
  const float* W1  = (const float*)d_in[1];  // (512,4080)
  const float* b1  = (const float*)d_in[2];  // (512,)
  const float* W2  = (const float*)d_in[3];  // (155,512)
  const float* b2  = (const float*)d_in[4];  // (155,)
  float* out = (float*)d_out;                // (64,155)

  // ws layout (floats): St | ht   (~1.2 MB total; tp buffer eliminated)
  float* St = (float*)d_ws;                  // 4080*64
  float* ht = St + (size_t)FAN1 * 64;        // 512*64

  sig_kernel<<<NPATH, 64, 0, stream>>>(inp, St, ht);
  gemm1_kernel<<<KSPL * 64 / 4, 256, 0, stream>>>(St, W1, ht);
  gemm2_kernel<<<NOUT, 256, 0, stream>>>(ht, W2, b1, b2, out);
}